// Round 1
// baseline (2040.704 us; speedup 1.0000x reference)
//
#include <hip/hip_runtime.h>
#include <hip/hip_bf16.h>
#include <stdint.h>

#define M_TIME 64
#define N_DICT 20000
#define B_VOX  8192

// Pack-transpose y into yt[n*128 + 0..63] = y_real[:,n], yt[n*128 + 64..127] = y_imag[:,n]
// so the argmax kernel's wave-uniform loads are contiguous (512 B per n).
__global__ void transpose_y(const float* __restrict__ yr, const float* __restrict__ yi,
                            float* __restrict__ yt) {
    int n = blockIdx.x * blockDim.x + threadIdx.x;
    int m = blockIdx.y;
    if (n < N_DICT) {
        yt[(size_t)n * 128 + m]      = yr[(size_t)m * N_DICT + n];
        yt[(size_t)n * 128 + 64 + m] = yi[(size_t)m * N_DICT + n];
    }
}

// Phase A: fused 4-dot GEMM + running argmax.
// One thread = one voxel. Input columns (64 ir + 64 ii) live in VGPRs across the
// whole n-loop. y accesses are wave-uniform -> scalar loads (SMEM pipe), leaving
// the VALU to issue almost nothing but v_fmac_f32.
template<bool TR>
__global__ __launch_bounds__(256, 3) void argmax_k(
    const float* __restrict__ ir, const float* __restrict__ ii,
    const float* __restrict__ yr, const float* __restrict__ yi,
    const float* __restrict__ yt,
    unsigned long long* __restrict__ best, int* __restrict__ idxout, int nchunk)
{
    int b  = blockIdx.x * 256 + threadIdx.x;
    int n0 = blockIdx.y * nchunk;
    int n1 = n0 + nchunk; if (n1 > N_DICT) n1 = N_DICT;

    float irv[M_TIME], iiv[M_TIME];
#pragma unroll
    for (int m = 0; m < M_TIME; ++m) {
        irv[m] = ir[m * B_VOX + b];
        iiv[m] = ii[m * B_VOX + b];
    }

    float bs = -1.0f;
    int   bn = 0;
    for (int n = n0; n < n1; ++n) {
        float rr = 0.f, ri = 0.f, s1 = 0.f, s2 = 0.f;
#pragma unroll
        for (int m = 0; m < M_TIME; ++m) {
            float a = TR ? yt[n * 128 + m]      : yr[m * N_DICT + n];
            float c = TR ? yt[n * 128 + 64 + m] : yi[m * N_DICT + n];
            rr = fmaf(irv[m], a, rr);
            ri = fmaf(irv[m], c, ri);
            s1 = fmaf(iiv[m], a, s1);
            s2 = fmaf(iiv[m], c, s2);
        }
        float sim = fmaf(rr, rr, fmaf(ri, ri, fmaf(s1, s1, s2 * s2)));
        if (sim > bs) { bs = sim; bn = n; }   // strict > keeps first (smallest n) on ties
    }

    if (best) {
        // sim >= 0 -> fp32 bits are monotone; inverted n so equal sims pick smaller n.
        unsigned long long p = (((unsigned long long)__float_as_uint(bs)) << 32)
                             | (unsigned long long)(0xFFFFFFFFu - (unsigned)bn);
        atomicMax(&best[b], p);
    } else {
        idxout[b] = bn;   // single-chunk fallback: no reduction needed
    }
}

// Phase B: gather chosen dictionary column, compute scales, write 4 output rows.
__global__ void finish_k(const float* __restrict__ ir, const float* __restrict__ ii,
                         const float* __restrict__ yr, const float* __restrict__ yi,
                         const float* __restrict__ yt, int tr,
                         const float* __restrict__ inv, const float* __restrict__ x1,
                         const float* __restrict__ x2,
                         const unsigned long long* __restrict__ best,
                         const int* __restrict__ idxin, float* __restrict__ out)
{
    int b = blockIdx.x * blockDim.x + threadIdx.x;
    int idx;
    if (best) idx = (int)(0xFFFFFFFFu - (unsigned)(best[b] & 0xFFFFFFFFull));
    else      idx = idxin[b];   // aliases out row 3: read before write, same thread — safe

    float ar = 0.f, ai = 0.f;
    for (int m = 0; m < M_TIME; ++m) {
        float a  = tr ? yt[(size_t)idx * 128 + m]      : yr[(size_t)m * N_DICT + idx];
        float c  = tr ? yt[(size_t)idx * 128 + 64 + m] : yi[(size_t)m * N_DICT + idx];
        float vr = ir[m * B_VOX + b];
        float vi = ii[m * B_VOX + b];
        ar = fmaf(a, vr, ar); ar = fmaf(c, vi, ar);     // sum yr*ir + yi*ii
        ai = fmaf(a, vi, ai); ai = fmaf(-c, vr, ai);    // sum yr*ii - yi*ir
    }
    float s = inv[idx];
    out[0 * B_VOX + b] = ar * s;
    out[1 * B_VOX + b] = ai * s;
    out[2 * B_VOX + b] = x1[idx];
    out[3 * B_VOX + b] = x2[idx];
}

extern "C" void kernel_launch(void* const* d_in, const int* in_sizes, int n_in,
                              void* d_out, int out_size, void* d_ws, size_t ws_size,
                              hipStream_t stream) {
    const float* ir  = (const float*)d_in[0];
    const float* ii  = (const float*)d_in[1];
    const float* yr  = (const float*)d_in[2];
    const float* yi  = (const float*)d_in[3];
    const float* inv = (const float*)d_in[4];
    const float* x1  = (const float*)d_in[5];
    const float* x2  = (const float*)d_in[6];
    float* out = (float*)d_out;

    const size_t need_best = (size_t)B_VOX * sizeof(unsigned long long);      // 64 KiB
    const size_t need_yt   = (size_t)N_DICT * 128 * sizeof(float);            // ~10.24 MB
    const bool have_ws = ws_size >= need_best;
    const bool have_yt = ws_size >= need_best + need_yt;

    unsigned long long* best = have_ws ? (unsigned long long*)d_ws : nullptr;
    float* yt   = have_yt ? (float*)((char*)d_ws + need_best) : nullptr;
    int*   idxo = have_ws ? nullptr : (int*)(out + 3 * B_VOX);

    if (have_yt) {
        transpose_y<<<dim3((N_DICT + 255) / 256, M_TIME), 256, 0, stream>>>(yr, yi, yt);
    }
    if (have_ws) {
        hipMemsetAsync(best, 0, need_best, stream);   // poison 0xAA would beat real sims
    }

    const int nchunks = have_ws ? 25 : 1;             // 25*800 = 20000
    const int nchunk  = (N_DICT + nchunks - 1) / nchunks;
    dim3 grid(B_VOX / 256, nchunks);

    if (have_yt)
        argmax_k<true ><<<grid, 256, 0, stream>>>(ir, ii, yr, yi, yt, best, idxo, nchunk);
    else
        argmax_k<false><<<grid, 256, 0, stream>>>(ir, ii, yr, yi, yt, best, idxo, nchunk);

    finish_k<<<B_VOX / 256, 256, 0, stream>>>(ir, ii, yr, yi, yt, (int)have_yt,
                                              inv, x1, x2, best, idxo, out);
}

// Round 2
// 1391.231 us; speedup vs baseline: 1.4668x; 1.4668x over previous
//
#include <hip/hip_runtime.h>
#include <hip/hip_bf16.h>
#include <stdint.h>

#define M_TIME 64
#define N_DICT 20000
#define B_VOX  8192
#define TN     32      // dictionary entries staged per LDS tile (32*128*4B = 16 KiB)
#define NCHUNK 50      // grid.y chunks; 50*400 = 20000 exactly
#define NPC    400     // n per chunk

// Pack-transpose y: yt[n*128 + m] = y_real[m,n] (m<64), yt[n*128+64+m] = y_imag[m,n].
__global__ void transpose_y(const float* __restrict__ yr, const float* __restrict__ yi,
                            float* __restrict__ yt) {
    int n = blockIdx.x * blockDim.x + threadIdx.x;
    int m = blockIdx.y;
    if (n < N_DICT) {
        yt[(size_t)n * 128 + m]      = yr[(size_t)m * N_DICT + n];
        yt[(size_t)n * 128 + 64 + m] = yi[(size_t)m * N_DICT + n];
    }
}

// Phase A: fused 4-dot + running argmax. One thread = one voxel; its 128 input
// values live in float4[16] register arrays for the whole chunk. y entries are
// staged into LDS per 32-n tile and read back with wave-uniform addresses
// (ds_read_b128 broadcast, conflict-free), so the VALU issues almost pure fmac.
__global__ __launch_bounds__(256, 2) void argmax_lds(
    const float* __restrict__ ir, const float* __restrict__ ii,
    const float4* __restrict__ yt4,
    unsigned long long* __restrict__ best)
{
    __shared__ float4 ys[TN * 32];     // [tile_n][32 quads: 16 yr + 16 yi]

    const int tid = threadIdx.x;
    const int b   = blockIdx.x * 256 + tid;
    const int n0  = blockIdx.y * NPC;
    const int n1  = n0 + NPC;          // NCHUNK*NPC == N_DICT, no clamp needed

    float4 irv[16], iiv[16];
#pragma unroll
    for (int q = 0; q < 16; ++q) {
        irv[q].x = ir[(4 * q + 0) * B_VOX + b];
        irv[q].y = ir[(4 * q + 1) * B_VOX + b];
        irv[q].z = ir[(4 * q + 2) * B_VOX + b];
        irv[q].w = ir[(4 * q + 3) * B_VOX + b];
        iiv[q].x = ii[(4 * q + 0) * B_VOX + b];
        iiv[q].y = ii[(4 * q + 1) * B_VOX + b];
        iiv[q].z = ii[(4 * q + 2) * B_VOX + b];
        iiv[q].w = ii[(4 * q + 3) * B_VOX + b];
    }

    float bs = -1.0f;
    int   bn = 0;

    for (int nb = n0; nb < n1; nb += TN) {
        const int cnt = (n1 - nb < TN) ? (n1 - nb) : TN;
        __syncthreads();                               // previous tile fully consumed
        {   // cooperative stage: contiguous float4s, coalesced
            const float4* src = yt4 + (size_t)nb * 32;
            const int total = cnt * 32;
            for (int j = tid; j < total; j += 256) ys[j] = src[j];
        }
        __syncthreads();

        for (int ln = 0; ln < cnt; ++ln) {
            const float4* yrow = &ys[ln * 32];         // wave-uniform base
            float rr = 0.f, ri = 0.f, s1 = 0.f, s2 = 0.f;
#pragma unroll
            for (int q = 0; q < 16; ++q) {
                float4 a = yrow[q];                    // yr quad, broadcast
                float4 c = yrow[16 + q];               // yi quad, broadcast
                rr = fmaf(irv[q].x, a.x, rr); rr = fmaf(irv[q].y, a.y, rr);
                rr = fmaf(irv[q].z, a.z, rr); rr = fmaf(irv[q].w, a.w, rr);
                ri = fmaf(irv[q].x, c.x, ri); ri = fmaf(irv[q].y, c.y, ri);
                ri = fmaf(irv[q].z, c.z, ri); ri = fmaf(irv[q].w, c.w, ri);
                s1 = fmaf(iiv[q].x, a.x, s1); s1 = fmaf(iiv[q].y, a.y, s1);
                s1 = fmaf(iiv[q].z, a.z, s1); s1 = fmaf(iiv[q].w, a.w, s1);
                s2 = fmaf(iiv[q].x, c.x, s2); s2 = fmaf(iiv[q].y, c.y, s2);
                s2 = fmaf(iiv[q].z, c.z, s2); s2 = fmaf(iiv[q].w, c.w, s2);
            }
            float sim = fmaf(rr, rr, fmaf(ri, ri, fmaf(s1, s1, s2 * s2)));
            if (sim > bs) { bs = sim; bn = nb + ln; }  // strict >: first index on ties
        }
    }

    // sim >= 0 -> fp32 bits monotone; inverted n so ties pick the smaller index.
    unsigned long long p = (((unsigned long long)__float_as_uint(bs)) << 32)
                         | (unsigned long long)(0xFFFFFFFFu - (unsigned)bn);
    atomicMax(&best[b], p);
}

// Fallback (no workspace for yt): round-1 style, direct strided reads.
__global__ __launch_bounds__(256, 3) void argmax_naive(
    const float* __restrict__ ir, const float* __restrict__ ii,
    const float* __restrict__ yr, const float* __restrict__ yi,
    int* __restrict__ idxout)
{
    int b = blockIdx.x * 256 + threadIdx.x;
    float irv[M_TIME], iiv[M_TIME];
#pragma unroll
    for (int m = 0; m < M_TIME; ++m) { irv[m] = ir[m*B_VOX+b]; iiv[m] = ii[m*B_VOX+b]; }
    float bs = -1.0f; int bn = 0;
    for (int n = 0; n < N_DICT; ++n) {
        float rr=0.f, ri=0.f, s1=0.f, s2=0.f;
#pragma unroll
        for (int m = 0; m < M_TIME; ++m) {
            float a = yr[m*N_DICT+n], c = yi[m*N_DICT+n];
            rr = fmaf(irv[m],a,rr); ri = fmaf(irv[m],c,ri);
            s1 = fmaf(iiv[m],a,s1); s2 = fmaf(iiv[m],c,s2);
        }
        float sim = fmaf(rr,rr, fmaf(ri,ri, fmaf(s1,s1, s2*s2)));
        if (sim > bs) { bs = sim; bn = n; }
    }
    idxout[b] = bn;
}

// Phase B: gather chosen column, compute scales, write the 4 output rows.
__global__ void finish_k(const float* __restrict__ ir, const float* __restrict__ ii,
                         const float* __restrict__ yr, const float* __restrict__ yi,
                         const float* __restrict__ yt, int tr,
                         const float* __restrict__ inv, const float* __restrict__ x1,
                         const float* __restrict__ x2,
                         const unsigned long long* __restrict__ best,
                         const int* __restrict__ idxin, float* __restrict__ out)
{
    int b = blockIdx.x * blockDim.x + threadIdx.x;
    int idx;
    if (best) idx = (int)(0xFFFFFFFFu - (unsigned)(best[b] & 0xFFFFFFFFull));
    else      idx = idxin[b];   // aliases out row 3: read-before-write, same thread

    float ar = 0.f, ai = 0.f;
    for (int m = 0; m < M_TIME; ++m) {
        float a  = tr ? yt[(size_t)idx * 128 + m]      : yr[(size_t)m * N_DICT + idx];
        float c  = tr ? yt[(size_t)idx * 128 + 64 + m] : yi[(size_t)m * N_DICT + idx];
        float vr = ir[m * B_VOX + b];
        float vi = ii[m * B_VOX + b];
        ar = fmaf(a, vr, ar); ar = fmaf(c, vi, ar);     // yr*ir + yi*ii
        ai = fmaf(a, vi, ai); ai = fmaf(-c, vr, ai);    // yr*ii - yi*ir
    }
    float s = inv[idx];
    out[0 * B_VOX + b] = ar * s;
    out[1 * B_VOX + b] = ai * s;
    out[2 * B_VOX + b] = x1[idx];
    out[3 * B_VOX + b] = x2[idx];
}

extern "C" void kernel_launch(void* const* d_in, const int* in_sizes, int n_in,
                              void* d_out, int out_size, void* d_ws, size_t ws_size,
                              hipStream_t stream) {
    const float* ir  = (const float*)d_in[0];
    const float* ii  = (const float*)d_in[1];
    const float* yr  = (const float*)d_in[2];
    const float* yi  = (const float*)d_in[3];
    const float* inv = (const float*)d_in[4];
    const float* x1  = (const float*)d_in[5];
    const float* x2  = (const float*)d_in[6];
    float* out = (float*)d_out;

    const size_t need_best = (size_t)B_VOX * sizeof(unsigned long long);      // 64 KiB
    const size_t need_yt   = (size_t)N_DICT * 128 * sizeof(float);            // ~10.24 MB
    const bool have_yt = ws_size >= need_best + need_yt;

    if (have_yt) {
        unsigned long long* best = (unsigned long long*)d_ws;
        float* yt = (float*)((char*)d_ws + need_best);

        transpose_y<<<dim3((N_DICT + 255) / 256, M_TIME), 256, 0, stream>>>(yr, yi, yt);
        hipMemsetAsync(best, 0, need_best, stream);   // 0xAA poison would beat real sims

        argmax_lds<<<dim3(B_VOX / 256, NCHUNK), 256, 0, stream>>>(
            ir, ii, (const float4*)yt, best);
        finish_k<<<B_VOX / 256, 256, 0, stream>>>(ir, ii, yr, yi, yt, 1,
                                                  inv, x1, x2, best, nullptr, out);
    } else {
        int* idxo = (int*)(out + 3 * B_VOX);
        argmax_naive<<<B_VOX / 256, 256, 0, stream>>>(ir, ii, yr, yi, idxo);
        finish_k<<<B_VOX / 256, 256, 0, stream>>>(ir, ii, yr, yi, nullptr, 0,
                                                  inv, x1, x2, nullptr, idxo, out);
    }
}

// Round 3
// 999.946 us; speedup vs baseline: 2.0408x; 1.3913x over previous
//
#include <hip/hip_runtime.h>
#include <hip/hip_bf16.h>
#include <stdint.h>

#define M_TIME 64
#define N_DICT 20000
#define B_VOX  8192

#define BLK_V  64     // voxels per block tile
#define BLK_N  128    // dict entries per block tile
#define KT     16     // k (m) steps per LDS stage
#define TH_V   4      // voxels per thread
#define TH_N   8      // dict entries per thread

// ---------------------------------------------------------------------------
// Phase A: register-tiled fp32 GEMM (4 dots) + fused argmax.
// 256 threads = 16(tx: voxel) x 16(ty: n). Per thread: 4 vox x 8 n outputs,
// 4 accumulators each (rr,ri,s1,s2) = 128 acc VGPRs; per k-step fragments are
// re-read from LDS (2 per-lane b128 + 4 broadcast b128), so the VALU stream is
// ~128 fmac per 6 LDS ops. This is the m93 shape the compiler allocates well.
// ---------------------------------------------------------------------------
__global__ __launch_bounds__(256, 2) void argmax_gemm(
    const float* __restrict__ ir, const float* __restrict__ ii,
    const float* __restrict__ yr, const float* __restrict__ yi,
    unsigned long long* __restrict__ best)
{
    __shared__ float ls_ir[KT * BLK_V];        // 4 KB  [km][64]
    __shared__ float ls_ii[KT * BLK_V];        // 4 KB
    __shared__ float ls_yr[KT * BLK_N];        // 8 KB  [km][128]
    __shared__ float ls_yi[KT * BLK_N];        // 8 KB
    __shared__ unsigned long long red[BLK_V * 16];  // 8 KB reduction scratch

    const int tid  = threadIdx.x;
    const int tx   = tid & 15;                 // voxel dim
    const int ty   = tid >> 4;                 // n dim
    const int vox0 = blockIdx.x * BLK_V;
    const int n0   = blockIdx.y * BLK_N;

    float rr[TH_V][TH_N], ri[TH_V][TH_N], s1[TH_V][TH_N], s2[TH_V][TH_N];
#pragma unroll
    for (int v = 0; v < TH_V; ++v)
#pragma unroll
        for (int j = 0; j < TH_N; ++j) { rr[v][j]=0.f; ri[v][j]=0.f; s1[v][j]=0.f; s2[v][j]=0.f; }

    for (int mt = 0; mt < M_TIME / KT; ++mt) {
        const int m0 = mt * KT;
        __syncthreads();                       // previous tile fully consumed
        {   // ---- stage ir/ii: 16 rows x 64 vox, 1 float4/thread each ----
            const int km = tid >> 4, c = (tid & 15) * 4;
            *(float4*)&ls_ir[km * BLK_V + c] =
                *(const float4*)&ir[(m0 + km) * B_VOX + vox0 + c];
            *(float4*)&ls_ii[km * BLK_V + c] =
                *(const float4*)&ii[(m0 + km) * B_VOX + vox0 + c];
            // ---- stage yr/yi: 16 rows x 128 n, 2 float4/thread each ----
#pragma unroll
            for (int r = 0; r < 2; ++r) {
                const int j   = tid + r * 256;
                const int km2 = j >> 5, c2 = (j & 31) * 4;
                const int n   = n0 + c2;
                float4 vr = make_float4(0.f, 0.f, 0.f, 0.f);
                float4 vi = make_float4(0.f, 0.f, 0.f, 0.f);
                if (n < N_DICT) {              // N_DICT%4==0: whole quad valid
                    vr = *(const float4*)&yr[(m0 + km2) * N_DICT + n];
                    vi = *(const float4*)&yi[(m0 + km2) * N_DICT + n];
                }
                *(float4*)&ls_yr[km2 * BLK_N + c2] = vr;
                *(float4*)&ls_yi[km2 * BLK_N + c2] = vi;
            }
        }
        __syncthreads();

#pragma unroll
        for (int km = 0; km < KT; ++km) {
            const float4 air = *(const float4*)&ls_ir[km * BLK_V + 4 * tx];
            const float4 aii = *(const float4*)&ls_ii[km * BLK_V + 4 * tx];
            const float4 y0r = *(const float4*)&ls_yr[km * BLK_N + 8 * ty];
            const float4 y1r = *(const float4*)&ls_yr[km * BLK_N + 8 * ty + 4];
            const float4 y0i = *(const float4*)&ls_yi[km * BLK_N + 8 * ty];
            const float4 y1i = *(const float4*)&ls_yi[km * BLK_N + 8 * ty + 4];
            const float av[TH_V] = { air.x, air.y, air.z, air.w };
            const float bv[TH_V] = { aii.x, aii.y, aii.z, aii.w };
            const float cr[TH_N] = { y0r.x, y0r.y, y0r.z, y0r.w, y1r.x, y1r.y, y1r.z, y1r.w };
            const float ci[TH_N] = { y0i.x, y0i.y, y0i.z, y0i.w, y1i.x, y1i.y, y1i.z, y1i.w };
#pragma unroll
            for (int v = 0; v < TH_V; ++v)
#pragma unroll
                for (int j = 0; j < TH_N; ++j) {
                    rr[v][j] = fmaf(av[v], cr[j], rr[v][j]);
                    ri[v][j] = fmaf(av[v], ci[j], ri[v][j]);
                    s1[v][j] = fmaf(bv[v], cr[j], s1[v][j]);
                    s2[v][j] = fmaf(bv[v], ci[j], s2[v][j]);
                }
        }
    }

    // ---- per-thread argmax over its 8 n, per voxel ----
    float bs[TH_V]; int bn[TH_V];
#pragma unroll
    for (int v = 0; v < TH_V; ++v) { bs[v] = -1.f; bn[v] = 0; }
#pragma unroll
    for (int j = 0; j < TH_N; ++j) {
        const int n = n0 + 8 * ty + j;         // ascending in j -> strict > = first idx
#pragma unroll
        for (int v = 0; v < TH_V; ++v) {
            float sim = fmaf(rr[v][j], rr[v][j],
                        fmaf(ri[v][j], ri[v][j],
                        fmaf(s1[v][j], s1[v][j], s2[v][j] * s2[v][j])));
            if (sim > bs[v]) { bs[v] = sim; bn[v] = n; }
        }
    }
    // padded n (>=N_DICT) carry sim==0, which never beats a real (positive) sim.
#pragma unroll
    for (int v = 0; v < TH_V; ++v) {
        unsigned long long p = (((unsigned long long)__float_as_uint(bs[v])) << 32)
                             | (unsigned long long)(0xFFFFFFFFu - (unsigned)bn[v]);
        red[(4 * tx + v) * 16 + ty] = p;
    }
    __syncthreads();
    if (tid < BLK_V) {
        unsigned long long m = 0;
#pragma unroll
        for (int j = 0; j < 16; ++j) {
            unsigned long long q = red[tid * 16 + j];
            if (q > m) m = q;
        }
        atomicMax(&best[vox0 + tid], m);
    }
}

// ---------------------------------------------------------------------------
// Fallback (no workspace): round-1 style direct argmax.
// ---------------------------------------------------------------------------
__global__ __launch_bounds__(256, 3) void argmax_naive(
    const float* __restrict__ ir, const float* __restrict__ ii,
    const float* __restrict__ yr, const float* __restrict__ yi,
    int* __restrict__ idxout)
{
    int b = blockIdx.x * 256 + threadIdx.x;
    float bs = -1.0f; int bn = 0;
    for (int n = 0; n < N_DICT; ++n) {
        float a_rr=0.f, a_ri=0.f, a_s1=0.f, a_s2=0.f;
        for (int m = 0; m < M_TIME; ++m) {
            float a = yr[m*N_DICT+n], c = yi[m*N_DICT+n];
            float vr = ir[m*B_VOX+b], vi = ii[m*B_VOX+b];
            a_rr = fmaf(vr,a,a_rr); a_ri = fmaf(vr,c,a_ri);
            a_s1 = fmaf(vi,a,a_s1); a_s2 = fmaf(vi,c,a_s2);
        }
        float sim = fmaf(a_rr,a_rr, fmaf(a_ri,a_ri, fmaf(a_s1,a_s1, a_s2*a_s2)));
        if (sim > bs) { bs = sim; bn = n; }
    }
    idxout[b] = bn;
}

// ---------------------------------------------------------------------------
// Phase B: gather chosen column, compute scales, write the 4 output rows.
// ---------------------------------------------------------------------------
__global__ void finish_k(const float* __restrict__ ir, const float* __restrict__ ii,
                         const float* __restrict__ yr, const float* __restrict__ yi,
                         const float* __restrict__ inv, const float* __restrict__ x1,
                         const float* __restrict__ x2,
                         const unsigned long long* __restrict__ best,
                         const int* __restrict__ idxin, float* __restrict__ out)
{
    int b = blockIdx.x * blockDim.x + threadIdx.x;
    int idx;
    if (best) idx = (int)(0xFFFFFFFFu - (unsigned)(best[b] & 0xFFFFFFFFull));
    else      idx = idxin[b];   // aliases out row 3: read-before-write, same thread

    float ar = 0.f, ai = 0.f;
    for (int m = 0; m < M_TIME; ++m) {
        float a  = yr[(size_t)m * N_DICT + idx];
        float c  = yi[(size_t)m * N_DICT + idx];
        float vr = ir[m * B_VOX + b];
        float vi = ii[m * B_VOX + b];
        ar = fmaf(a, vr, ar); ar = fmaf(c, vi, ar);     // yr*ir + yi*ii
        ai = fmaf(a, vi, ai); ai = fmaf(-c, vr, ai);    // yr*ii - yi*ir
    }
    float s = inv[idx];
    out[0 * B_VOX + b] = ar * s;
    out[1 * B_VOX + b] = ai * s;
    out[2 * B_VOX + b] = x1[idx];
    out[3 * B_VOX + b] = x2[idx];
}

extern "C" void kernel_launch(void* const* d_in, const int* in_sizes, int n_in,
                              void* d_out, int out_size, void* d_ws, size_t ws_size,
                              hipStream_t stream) {
    const float* ir  = (const float*)d_in[0];
    const float* ii  = (const float*)d_in[1];
    const float* yr  = (const float*)d_in[2];
    const float* yi  = (const float*)d_in[3];
    const float* inv = (const float*)d_in[4];
    const float* x1  = (const float*)d_in[5];
    const float* x2  = (const float*)d_in[6];
    float* out = (float*)d_out;

    const size_t need_best = (size_t)B_VOX * sizeof(unsigned long long);   // 64 KiB

    if (ws_size >= need_best) {
        unsigned long long* best = (unsigned long long*)d_ws;
        hipMemsetAsync(best, 0, need_best, stream);   // 0xAA poison would beat real sims

        dim3 grid(B_VOX / BLK_V, (N_DICT + BLK_N - 1) / BLK_N);   // 128 x 157
        argmax_gemm<<<grid, 256, 0, stream>>>(ir, ii, yr, yi, best);
        finish_k<<<B_VOX / 256, 256, 0, stream>>>(ir, ii, yr, yi,
                                                  inv, x1, x2, best, nullptr, out);
    } else {
        int* idxo = (int*)(out + 3 * B_VOX);
        argmax_naive<<<B_VOX / 256, 256, 0, stream>>>(ir, ii, yr, yi, idxo);
        finish_k<<<B_VOX / 256, 256, 0, stream>>>(ir, ii, yr, yi,
                                                  inv, x1, x2, nullptr, idxo, out);
    }
}

// Round 5
// 539.922 us; speedup vs baseline: 3.7796x; 1.8520x over previous
//
#include <hip/hip_runtime.h>
#include <hip/hip_bf16.h>
#include <stdint.h>

#define M_TIME 64
#define N_DICT 20000
#define B_VOX  8192

#define CH     32     // n-chunks (grid.y); chunk = 625 n, top-2 candidates each
#define CHN    625
#define NSTEPS 10     // 10*64 = 640 n per chunk (15 overlap into next, harmless)

typedef short v8s __attribute__((ext_vector_type(8)));   // 8 bf16 (bit pattern)
typedef float v4f __attribute__((ext_vector_type(4)));

__device__ __forceinline__ unsigned short bf16h(float x) {   // RNE fp32->bf16
    unsigned int u = __float_as_uint(x);
    return (unsigned short)((u + 0x7fffu + ((u >> 16) & 1u)) >> 16);
}
__device__ __forceinline__ float bf16f(unsigned short h) {
    return __uint_as_float(((unsigned int)h) << 16);
}
__device__ __forceinline__ unsigned long long u64max(unsigned long long a, unsigned long long b) { return a > b ? a : b; }
__device__ __forceinline__ unsigned long long u64min(unsigned long long a, unsigned long long b) { return a < b ? a : b; }

// ---------------------------------------------------------------------------
// Phase A: bf16-split MFMA GEMM (3-term fp32 emulation) + per-chunk top-2.
// A-operand = y (rows = n), B-operand = input (cols = voxel).
// Block: 64 vox x 64 n-step; 4 waves = 2(wb: voxel) x 2(wn: n); wave tile 32x32.
// RACE FIX (round 5): waves (wb,0) and (wb,1) cover the same voxels over
// different n-halves; their top-2 sets are merged via LDS with a single
// writer (wn==0), instead of both racing on the same cand slots.
// ---------------------------------------------------------------------------
__global__ __launch_bounds__(256, 2) void gemm_mfma(
    const float* __restrict__ ir, const float* __restrict__ ii,
    const float* __restrict__ yr, const float* __restrict__ yi,
    unsigned long long* __restrict__ cand)
{
    __shared__ ushort4 ys[4 * 16 * 64];   // 32 KB: [t(4)][kq(16)][n(64)], 4 bf16 each
    __shared__ unsigned long long xm[2][2][16][2];  // 1 KB: [wb][bt][col][a1,a2]

    const int tid  = threadIdx.x;
    const int wave = tid >> 6, lane = tid & 63;
    const int quad = lane >> 4, col = lane & 15;
    const int wb   = wave >> 1, wn = wave & 1;
    const int vox_w = blockIdx.x * 64 + wb * 32;
    const int chunk = blockIdx.y;
    const int nbase = chunk * CHN;

    // ---- persistent input B-frags: [arr(ir,ii)][bt][h] hi/lo, built from global ----
    v8s fh[2][2][2], fl[2][2][2];
#pragma unroll
    for (int arr = 0; arr < 2; ++arr) {
        const float* P = arr ? ii : ir;
#pragma unroll
        for (int bt = 0; bt < 2; ++bt) {
            const int b = vox_w + bt * 16 + col;
#pragma unroll
            for (int h = 0; h < 2; ++h) {
                v8s H, L;
#pragma unroll
                for (int j = 0; j < 8; ++j) {
                    const int k = h * 32 + quad * 8 + j;
                    float x = P[k * B_VOX + b];
                    unsigned short hb = bf16h(x);
                    H[j] = (short)hb;
                    L[j] = (short)bf16h(x - bf16f(hb));
                }
                fh[arr][bt][h] = H; fl[arr][bt][h] = L;
            }
        }
    }

    unsigned long long t2a[2] = {0ull, 0ull}, t2b[2] = {0ull, 0ull};

    for (int step = 0; step < NSTEPS; ++step) {
        const int sn0 = nbase + step * 64;
        __syncthreads();                       // previous tile consumed
        // ---- stage y (64 n x 64 k x {r,i}), split to bf16 hi/lo in LDS ----
#pragma unroll
        for (int p = 0; p < 8; ++p) {
            const int u = tid + p * 256;       // 2048 units
            const int n_l = u & 63, kq = (u >> 6) & 15, arr = u >> 10;
            const float* P = arr ? yi : yr;
            const int n_g = sn0 + n_l;
            float v0 = 0.f, v1 = 0.f, v2 = 0.f, v3 = 0.f;
            if (n_g < N_DICT) {
                v0 = P[(kq * 4 + 0) * N_DICT + n_g];
                v1 = P[(kq * 4 + 1) * N_DICT + n_g];
                v2 = P[(kq * 4 + 2) * N_DICT + n_g];
                v3 = P[(kq * 4 + 3) * N_DICT + n_g];
            }
            ushort4 H, L;
            H.x = bf16h(v0); L.x = bf16h(v0 - bf16f(H.x));
            H.y = bf16h(v1); L.y = bf16h(v1 - bf16f(H.y));
            H.z = bf16h(v2); L.z = bf16h(v2 - bf16f(H.z));
            H.w = bf16h(v3); L.w = bf16h(v3 - bf16f(H.w));
            ys[((arr * 2 + 0) * 16 + kq) * 64 + n_l] = H;   // t = 2*arr   (hi)
            ys[((arr * 2 + 1) * 16 + kq) * 64 + n_l] = L;   // t = 2*arr+1 (lo)
        }
        __syncthreads();

        v4f acc[2][2][4];                      // [bt][nt][rr,ri,s1,s2]
#pragma unroll
        for (int bt = 0; bt < 2; ++bt)
#pragma unroll
            for (int nt = 0; nt < 2; ++nt)
#pragma unroll
                for (int d = 0; d < 4; ++d) acc[bt][nt][d] = (v4f){0.f, 0.f, 0.f, 0.f};

#pragma unroll
        for (int h = 0; h < 2; ++h) {
            const int kq0 = h * 8 + quad * 2;
#pragma unroll
            for (int nt = 0; nt < 2; ++nt) {
                const int nrow = (wn * 2 + nt) * 16 + col;
                v8s yf[4];                     // yrh, yrl, yih, yil
#pragma unroll
                for (int t = 0; t < 4; ++t) {
                    ushort4 lo = ys[(t * 16 + kq0    ) * 64 + nrow];
                    ushort4 hi = ys[(t * 16 + kq0 + 1) * 64 + nrow];
                    v8s f;
                    f[0] = (short)lo.x; f[1] = (short)lo.y; f[2] = (short)lo.z; f[3] = (short)lo.w;
                    f[4] = (short)hi.x; f[5] = (short)hi.y; f[6] = (short)hi.z; f[7] = (short)hi.w;
                    yf[t] = f;
                }
#pragma unroll
                for (int bt = 0; bt < 2; ++bt) {
#define MF(A, B, C) C = __builtin_amdgcn_mfma_f32_16x16x32_bf16(A, B, C, 0, 0, 0)
                    MF(yf[0], fh[0][bt][h], acc[bt][nt][0]);   // rr: yrh*irh
                    MF(yf[0], fl[0][bt][h], acc[bt][nt][0]);   //     yrh*irl
                    MF(yf[1], fh[0][bt][h], acc[bt][nt][0]);   //     yrl*irh
                    MF(yf[2], fh[0][bt][h], acc[bt][nt][1]);   // ri: yih*irh
                    MF(yf[2], fl[0][bt][h], acc[bt][nt][1]);
                    MF(yf[3], fh[0][bt][h], acc[bt][nt][1]);
                    MF(yf[0], fh[1][bt][h], acc[bt][nt][2]);   // s1: yrh*iih
                    MF(yf[0], fl[1][bt][h], acc[bt][nt][2]);
                    MF(yf[1], fh[1][bt][h], acc[bt][nt][2]);
                    MF(yf[2], fh[1][bt][h], acc[bt][nt][3]);   // s2: yih*iih
                    MF(yf[2], fl[1][bt][h], acc[bt][nt][3]);
                    MF(yf[3], fh[1][bt][h], acc[bt][nt][3]);
#undef MF
                }
            }
        }

        // ---- per-step sim + top-2 update (C/D: row = quad*4+r, col = lane&15) ----
#pragma unroll
        for (int bt = 0; bt < 2; ++bt)
#pragma unroll
            for (int nt = 0; nt < 2; ++nt) {
                v4f RR = acc[bt][nt][0], RI = acc[bt][nt][1];
                v4f S1 = acc[bt][nt][2], S2 = acc[bt][nt][3];
#pragma unroll
                for (int r = 0; r < 4; ++r) {
                    float s = fmaf(RR[r], RR[r], fmaf(RI[r], RI[r],
                              fmaf(S1[r], S1[r], S2[r] * S2[r])));
                    const int n_g = sn0 + (wn * 2 + nt) * 16 + quad * 4 + r;
                    unsigned long long p =
                        (((unsigned long long)__float_as_uint(s)) << 32)
                      | (unsigned long long)(0xFFFFFFFFu - (unsigned)n_g);
                    if (p > t2a[bt])      { t2b[bt] = t2a[bt]; t2a[bt] = p; }
                    else if (p > t2b[bt]) { t2b[bt] = p; }
                }
            }
    }

    // ---- cross-lane top-2 merge over quads (lanes c, c+16, c+32, c+48) ----
    unsigned long long fa1[2], fa2[2];
#pragma unroll
    for (int bt = 0; bt < 2; ++bt) {
        unsigned long long a1 = t2a[bt], a2 = t2b[bt];
#pragma unroll
        for (int d = 16; d <= 32; d <<= 1) {
            unsigned long long b1 = __shfl_xor(a1, d, 64);
            unsigned long long b2 = __shfl_xor(a2, d, 64);
            unsigned long long m1 = u64max(a1, b1);
            unsigned long long m2 = u64max(u64min(a1, b1), u64max(a2, b2));
            a1 = m1; a2 = m2;
        }
        fa1[bt] = a1; fa2[bt] = a2;
    }
    // ---- cross-wave (wn) merge: wn==1 publishes, wn==0 merges and writes ----
    __syncthreads();                            // all compute on ys done anyway
    if (wn == 1 && lane < 16) {
#pragma unroll
        for (int bt = 0; bt < 2; ++bt) {
            xm[wb][bt][lane][0] = fa1[bt];
            xm[wb][bt][lane][1] = fa2[bt];
        }
    }
    __syncthreads();
    if (wn == 0 && lane < 16) {
#pragma unroll
        for (int bt = 0; bt < 2; ++bt) {
            unsigned long long b1 = xm[wb][bt][lane][0];
            unsigned long long b2 = xm[wb][bt][lane][1];
            unsigned long long m1 = u64max(fa1[bt], b1);
            unsigned long long m2 = u64max(u64min(fa1[bt], b1), u64max(fa2[bt], b2));
            const size_t vox = vox_w + bt * 16 + lane;
            cand[vox * 64 + chunk * 2 + 0] = m1;
            cand[vox * 64 + chunk * 2 + 1] = m2;
        }
    }
}

// ---------------------------------------------------------------------------
// Phase B: exact fp32 rescore of candidates within 1% of the approx max.
// One wave per voxel (64 candidate slots).
// ---------------------------------------------------------------------------
__global__ __launch_bounds__(256) void rescore_k(
    const float* __restrict__ ir, const float* __restrict__ ii,
    const float* __restrict__ yr, const float* __restrict__ yi,
    const unsigned long long* __restrict__ cand, int* __restrict__ idx_sel)
{
    const int tid  = threadIdx.x;
    const int vox  = blockIdx.x * 4 + (tid >> 6);
    const int slot = tid & 63;

    unsigned long long p = cand[(size_t)vox * 64 + slot];
    float sa = __uint_as_float((unsigned int)(p >> 32));
    unsigned int nn = 0xFFFFFFFFu - (unsigned int)(p & 0xFFFFFFFFull);

    float amax = sa;
#pragma unroll
    for (int d = 1; d <= 32; d <<= 1) amax = fmaxf(amax, __shfl_xor(amax, d, 64));

    unsigned long long q = 0ull;
    if (nn < N_DICT && sa >= 0.99f * amax) {
        float rr = 0.f, ri = 0.f, s1 = 0.f, s2 = 0.f;
        for (int m = 0; m < M_TIME; ++m) {
            float a  = yr[(size_t)m * N_DICT + nn];
            float c  = yi[(size_t)m * N_DICT + nn];
            float vr = ir[m * B_VOX + vox];
            float vi = ii[m * B_VOX + vox];
            rr = fmaf(vr, a, rr); ri = fmaf(vr, c, ri);
            s1 = fmaf(vi, a, s1); s2 = fmaf(vi, c, s2);
        }
        float s = fmaf(rr, rr, fmaf(ri, ri, fmaf(s1, s1, s2 * s2)));
        q = (((unsigned long long)__float_as_uint(s)) << 32)
          | (unsigned long long)(0xFFFFFFFFu - nn);          // ties -> smaller n
    }
#pragma unroll
    for (int d = 1; d <= 32; d <<= 1) q = u64max(q, __shfl_xor(q, d, 64));
    if (slot == 0) idx_sel[vox] = (int)(0xFFFFFFFFu - (unsigned int)(q & 0xFFFFFFFFull));
}

// ---------------------------------------------------------------------------
// Fallback (tiny ws): fp32 brute-force argmax.
// ---------------------------------------------------------------------------
__global__ __launch_bounds__(256, 3) void argmax_naive(
    const float* __restrict__ ir, const float* __restrict__ ii,
    const float* __restrict__ yr, const float* __restrict__ yi,
    int* __restrict__ idxout)
{
    int b = blockIdx.x * 256 + threadIdx.x;
    float bs = -1.0f; int bn = 0;
    for (int n = 0; n < N_DICT; ++n) {
        float a_rr = 0.f, a_ri = 0.f, a_s1 = 0.f, a_s2 = 0.f;
        for (int m = 0; m < M_TIME; ++m) {
            float a = yr[m * N_DICT + n], c = yi[m * N_DICT + n];
            float vr = ir[m * B_VOX + b], vi = ii[m * B_VOX + b];
            a_rr = fmaf(vr, a, a_rr); a_ri = fmaf(vr, c, a_ri);
            a_s1 = fmaf(vi, a, a_s1); a_s2 = fmaf(vi, c, a_s2);
        }
        float sim = fmaf(a_rr, a_rr, fmaf(a_ri, a_ri, fmaf(a_s1, a_s1, a_s2 * a_s2)));
        if (sim > bs) { bs = sim; bn = n; }
    }
    idxout[b] = bn;
}

// ---------------------------------------------------------------------------
// Phase C: gather chosen column, compute scales, write 4 output rows.
// ---------------------------------------------------------------------------
__global__ void finish_k(const float* __restrict__ ir, const float* __restrict__ ii,
                         const float* __restrict__ yr, const float* __restrict__ yi,
                         const float* __restrict__ inv, const float* __restrict__ x1,
                         const float* __restrict__ x2,
                         const int* __restrict__ idxin, float* __restrict__ out)
{
    int b = blockIdx.x * blockDim.x + threadIdx.x;
    int idx = idxin[b];
    float ar = 0.f, ai = 0.f;
    for (int m = 0; m < M_TIME; ++m) {
        float a  = yr[(size_t)m * N_DICT + idx];
        float c  = yi[(size_t)m * N_DICT + idx];
        float vr = ir[m * B_VOX + b];
        float vi = ii[m * B_VOX + b];
        ar = fmaf(a, vr, ar); ar = fmaf(c, vi, ar);     // yr*ir + yi*ii
        ai = fmaf(a, vi, ai); ai = fmaf(-c, vr, ai);    // yr*ii - yi*ir
    }
    float s = inv[idx];
    out[0 * B_VOX + b] = ar * s;
    out[1 * B_VOX + b] = ai * s;
    out[2 * B_VOX + b] = x1[idx];
    out[3 * B_VOX + b] = x2[idx];
}

extern "C" void kernel_launch(void* const* d_in, const int* in_sizes, int n_in,
                              void* d_out, int out_size, void* d_ws, size_t ws_size,
                              hipStream_t stream) {
    const float* ir  = (const float*)d_in[0];
    const float* ii  = (const float*)d_in[1];
    const float* yr  = (const float*)d_in[2];
    const float* yi  = (const float*)d_in[3];
    const float* inv = (const float*)d_in[4];
    const float* x1  = (const float*)d_in[5];
    const float* x2  = (const float*)d_in[6];
    float* out = (float*)d_out;

    const size_t need_cand = (size_t)B_VOX * 64 * sizeof(unsigned long long); // 4 MB
    const size_t need_idx  = (size_t)B_VOX * sizeof(int);                     // 32 KB

    if (ws_size >= need_cand + need_idx) {
        unsigned long long* cand = (unsigned long long*)d_ws;
        int* idx_sel = (int*)((char*)d_ws + need_cand);

        gemm_mfma<<<dim3(B_VOX / 64, CH), 256, 0, stream>>>(ir, ii, yr, yi, cand);
        rescore_k<<<B_VOX / 4, 256, 0, stream>>>(ir, ii, yr, yi, cand, idx_sel);
        finish_k<<<B_VOX / 256, 256, 0, stream>>>(ir, ii, yr, yi,
                                                  inv, x1, x2, idx_sel, out);
    } else {
        int* idxo = (int*)(out + 3 * B_VOX);   // alias out row 3 (read-before-write)
        argmax_naive<<<B_VOX / 256, 256, 0, stream>>>(ir, ii, yr, yi, idxo);
        finish_k<<<B_VOX / 256, 256, 0, stream>>>(ir, ii, yr, yi,
                                                  inv, x1, x2, idxo, out);
    }
}

// Round 6
// 347.665 us; speedup vs baseline: 5.8698x; 1.5530x over previous
//
#include <hip/hip_runtime.h>
#include <hip/hip_bf16.h>
#include <stdint.h>

#define M_TIME 64
#define N_DICT 20000
#define B_VOX  8192

#define NTILES 313    // ceil(20000/64); last tile padded with zeros

typedef short v8s __attribute__((ext_vector_type(8)));   // 8 bf16 (bit pattern)
typedef float v4f __attribute__((ext_vector_type(4)));

__device__ __forceinline__ unsigned short bf16h(float x) {   // RNE fp32->bf16
    unsigned int u = __float_as_uint(x);
    return (unsigned short)((u + 0x7fffu + ((u >> 16) & 1u)) >> 16);
}
__device__ __forceinline__ float bf16f(unsigned short h) {
    return __uint_as_float(((unsigned int)h) << 16);
}
__device__ __forceinline__ unsigned long long u64max(unsigned long long a, unsigned long long b) { return a > b ? a : b; }
__device__ __forceinline__ unsigned long long u64min(unsigned long long a, unsigned long long b) { return a < b ? a : b; }

// ---------------------------------------------------------------------------
// Prepass: split y into bf16 hi/lo ONCE, packed in the exact LDS tile layout:
// yp[((T*4 + t)*16 + kq)*64 + n_l], t = {yr_hi, yr_lo, yi_hi, yi_lo},
// k = kq*4 + component. Removes the 128x-redundant per-block conversion that
// capped round 5 at MfmaUtil 24%.
// ---------------------------------------------------------------------------
__global__ __launch_bounds__(256) void split_y(
    const float* __restrict__ yr, const float* __restrict__ yi,
    ushort4* __restrict__ yp)
{
    const int u = blockIdx.x * 256 + threadIdx.x;   // [arr][T][kq][n_l]
    const int n_l = u & 63;
    const int kq  = (u >> 6) & 15;
    const int T   = (u >> 10) % NTILES;
    const int arr = u / (NTILES * 1024);
    if (arr > 1) return;
    const float* P = arr ? yi : yr;
    const int n_g = T * 64 + n_l;
    float v0 = 0.f, v1 = 0.f, v2 = 0.f, v3 = 0.f;
    if (n_g < N_DICT) {
        v0 = P[(kq * 4 + 0) * N_DICT + n_g];
        v1 = P[(kq * 4 + 1) * N_DICT + n_g];
        v2 = P[(kq * 4 + 2) * N_DICT + n_g];
        v3 = P[(kq * 4 + 3) * N_DICT + n_g];
    }
    ushort4 H, L;
    H.x = bf16h(v0); L.x = bf16h(v0 - bf16f(H.x));
    H.y = bf16h(v1); L.y = bf16h(v1 - bf16f(H.y));
    H.z = bf16h(v2); L.z = bf16h(v2 - bf16f(H.z));
    H.w = bf16h(v3); L.w = bf16h(v3 - bf16f(H.w));
    yp[(((size_t)T * 4 + arr * 2 + 0) * 16 + kq) * 64 + n_l] = H;
    yp[(((size_t)T * 4 + arr * 2 + 1) * 16 + kq) * 64 + n_l] = L;
}

// ---------------------------------------------------------------------------
// Phase A (fast path): bf16-split MFMA GEMM reading pre-split y tiles.
// Staging = straight 32 KB copy per 64-n tile (no conversion VALU).
// Block: 64 vox x 64 n; 4 waves = 2(wb) x 2(wn); per-chunk top-2 candidates,
// wn-waves merged via LDS with single writer (round-5 race fix kept).
// ---------------------------------------------------------------------------
__global__ __launch_bounds__(256, 2) void gemm_pre(
    const float* __restrict__ ir, const float* __restrict__ ii,
    const ushort4* __restrict__ yp,
    unsigned long long* __restrict__ cand, int tpc, int slots)
{
    __shared__ float4 ys4[2048];                    // 32 KB tile, 16B-aligned
    __shared__ unsigned long long xm[2][2][16][2];  // [wb][bt][col][a1,a2]
    ushort4* ysu = (ushort4*)ys4;

    const int tid  = threadIdx.x;
    const int wave = tid >> 6, lane = tid & 63;
    const int quad = lane >> 4, col = lane & 15;
    const int wb   = wave >> 1, wn = wave & 1;
    const int vox_w = blockIdx.x * 64 + wb * 32;
    const int chunk = blockIdx.y;
    const int T0 = chunk * tpc;
    const int T1 = (T0 + tpc < NTILES) ? T0 + tpc : NTILES;

    // ---- persistent input B-frags: [arr][bt][h] hi/lo (once per block) ----
    v8s fh[2][2][2], fl[2][2][2];
#pragma unroll
    for (int arr = 0; arr < 2; ++arr) {
        const float* P = arr ? ii : ir;
#pragma unroll
        for (int bt = 0; bt < 2; ++bt) {
            const int b = vox_w + bt * 16 + col;
#pragma unroll
            for (int h = 0; h < 2; ++h) {
                v8s H, L;
#pragma unroll
                for (int j = 0; j < 8; ++j) {
                    const int k = h * 32 + quad * 8 + j;
                    float x = P[k * B_VOX + b];
                    unsigned short hb = bf16h(x);
                    H[j] = (short)hb;
                    L[j] = (short)bf16h(x - bf16f(hb));
                }
                fh[arr][bt][h] = H; fl[arr][bt][h] = L;
            }
        }
    }

    unsigned long long t2a[2] = {0ull, 0ull}, t2b[2] = {0ull, 0ull};

    for (int T = T0; T < T1; ++T) {
        __syncthreads();                       // previous tile consumed
        {   // ---- stage: contiguous 32 KB copy, 8 float4 per thread ----
            const float4* src = (const float4*)(yp + (size_t)T * 4096);
#pragma unroll
            for (int p = 0; p < 8; ++p) ys4[tid + p * 256] = src[tid + p * 256];
        }
        __syncthreads();

        v4f acc[2][2][4];                      // [bt][nt][rr,ri,s1,s2]
#pragma unroll
        for (int bt = 0; bt < 2; ++bt)
#pragma unroll
            for (int nt = 0; nt < 2; ++nt)
#pragma unroll
                for (int d = 0; d < 4; ++d) acc[bt][nt][d] = (v4f){0.f, 0.f, 0.f, 0.f};

#pragma unroll
        for (int h = 0; h < 2; ++h) {
            const int kq0 = h * 8 + quad * 2;
#pragma unroll
            for (int nt = 0; nt < 2; ++nt) {
                const int nrow = (wn * 2 + nt) * 16 + col;
                v8s yf[4];                     // yrh, yrl, yih, yil
#pragma unroll
                for (int t = 0; t < 4; ++t) {
                    ushort4 lo = ysu[(t * 16 + kq0    ) * 64 + nrow];
                    ushort4 hi = ysu[(t * 16 + kq0 + 1) * 64 + nrow];
                    v8s f;
                    f[0] = (short)lo.x; f[1] = (short)lo.y; f[2] = (short)lo.z; f[3] = (short)lo.w;
                    f[4] = (short)hi.x; f[5] = (short)hi.y; f[6] = (short)hi.z; f[7] = (short)hi.w;
                    yf[t] = f;
                }
#pragma unroll
                for (int bt = 0; bt < 2; ++bt) {
#define MF(A, B, C) C = __builtin_amdgcn_mfma_f32_16x16x32_bf16(A, B, C, 0, 0, 0)
                    MF(yf[0], fh[0][bt][h], acc[bt][nt][0]);   // rr: yrh*irh
                    MF(yf[0], fl[0][bt][h], acc[bt][nt][0]);   //     yrh*irl
                    MF(yf[1], fh[0][bt][h], acc[bt][nt][0]);   //     yrl*irh
                    MF(yf[2], fh[0][bt][h], acc[bt][nt][1]);   // ri
                    MF(yf[2], fl[0][bt][h], acc[bt][nt][1]);
                    MF(yf[3], fh[0][bt][h], acc[bt][nt][1]);
                    MF(yf[0], fh[1][bt][h], acc[bt][nt][2]);   // s1
                    MF(yf[0], fl[1][bt][h], acc[bt][nt][2]);
                    MF(yf[1], fh[1][bt][h], acc[bt][nt][2]);
                    MF(yf[2], fh[1][bt][h], acc[bt][nt][3]);   // s2
                    MF(yf[2], fl[1][bt][h], acc[bt][nt][3]);
                    MF(yf[3], fh[1][bt][h], acc[bt][nt][3]);
#undef MF
                }
            }
        }

        // ---- sim + top-2 (C/D: row = quad*4+r, col = lane&15) ----
#pragma unroll
        for (int bt = 0; bt < 2; ++bt)
#pragma unroll
            for (int nt = 0; nt < 2; ++nt) {
                v4f RR = acc[bt][nt][0], RI = acc[bt][nt][1];
                v4f S1 = acc[bt][nt][2], S2 = acc[bt][nt][3];
#pragma unroll
                for (int r = 0; r < 4; ++r) {
                    float s = fmaf(RR[r], RR[r], fmaf(RI[r], RI[r],
                              fmaf(S1[r], S1[r], S2[r] * S2[r])));
                    const int n_g = T * 64 + (wn * 2 + nt) * 16 + quad * 4 + r;
                    unsigned long long p =
                        (((unsigned long long)__float_as_uint(s)) << 32)
                      | (unsigned long long)(0xFFFFFFFFu - (unsigned)n_g);
                    if (p > t2a[bt])      { t2b[bt] = t2a[bt]; t2a[bt] = p; }
                    else if (p > t2b[bt]) { t2b[bt] = p; }
                }
            }
    }

    // ---- cross-lane top-2 merge over quads ----
    unsigned long long fa1[2], fa2[2];
#pragma unroll
    for (int bt = 0; bt < 2; ++bt) {
        unsigned long long a1 = t2a[bt], a2 = t2b[bt];
#pragma unroll
        for (int d = 16; d <= 32; d <<= 1) {
            unsigned long long b1 = __shfl_xor(a1, d, 64);
            unsigned long long b2 = __shfl_xor(a2, d, 64);
            unsigned long long m1 = u64max(a1, b1);
            unsigned long long m2 = u64max(u64min(a1, b1), u64max(a2, b2));
            a1 = m1; a2 = m2;
        }
        fa1[bt] = a1; fa2[bt] = a2;
    }
    // ---- cross-wave (wn) merge: wn==1 publishes, wn==0 writes ----
    __syncthreads();
    if (wn == 1 && lane < 16) {
#pragma unroll
        for (int bt = 0; bt < 2; ++bt) { xm[wb][bt][lane][0] = fa1[bt]; xm[wb][bt][lane][1] = fa2[bt]; }
    }
    __syncthreads();
    if (wn == 0 && lane < 16) {
#pragma unroll
        for (int bt = 0; bt < 2; ++bt) {
            unsigned long long b1 = xm[wb][bt][lane][0];
            unsigned long long b2 = xm[wb][bt][lane][1];
            unsigned long long m1 = u64max(fa1[bt], b1);
            unsigned long long m2 = u64max(u64min(fa1[bt], b1), u64max(fa2[bt], b2));
            const size_t vox = vox_w + bt * 16 + lane;
            cand[vox * slots + chunk * 2 + 0] = m1;
            cand[vox * slots + chunk * 2 + 1] = m2;
        }
    }
}

// ---------------------------------------------------------------------------
// Phase A (fallback path, proven round 5): in-kernel y conversion.
// ---------------------------------------------------------------------------
#define R5_CH  32
#define R5_CHN 625
#define R5_NST 10
__global__ __launch_bounds__(256, 2) void gemm_mfma(
    const float* __restrict__ ir, const float* __restrict__ ii,
    const float* __restrict__ yr, const float* __restrict__ yi,
    unsigned long long* __restrict__ cand)
{
    __shared__ ushort4 ys[4 * 16 * 64];
    __shared__ unsigned long long xm[2][2][16][2];
    const int tid  = threadIdx.x;
    const int wave = tid >> 6, lane = tid & 63;
    const int quad = lane >> 4, col = lane & 15;
    const int wb   = wave >> 1, wn = wave & 1;
    const int vox_w = blockIdx.x * 64 + wb * 32;
    const int chunk = blockIdx.y;
    const int nbase = chunk * R5_CHN;

    v8s fh[2][2][2], fl[2][2][2];
#pragma unroll
    for (int arr = 0; arr < 2; ++arr) {
        const float* P = arr ? ii : ir;
#pragma unroll
        for (int bt = 0; bt < 2; ++bt) {
            const int b = vox_w + bt * 16 + col;
#pragma unroll
            for (int h = 0; h < 2; ++h) {
                v8s H, L;
#pragma unroll
                for (int j = 0; j < 8; ++j) {
                    const int k = h * 32 + quad * 8 + j;
                    float x = P[k * B_VOX + b];
                    unsigned short hb = bf16h(x);
                    H[j] = (short)hb; L[j] = (short)bf16h(x - bf16f(hb));
                }
                fh[arr][bt][h] = H; fl[arr][bt][h] = L;
            }
        }
    }
    unsigned long long t2a[2] = {0ull, 0ull}, t2b[2] = {0ull, 0ull};
    for (int step = 0; step < R5_NST; ++step) {
        const int sn0 = nbase + step * 64;
        __syncthreads();
#pragma unroll
        for (int p = 0; p < 8; ++p) {
            const int u = tid + p * 256;
            const int n_l = u & 63, kq = (u >> 6) & 15, arr = u >> 10;
            const float* P = arr ? yi : yr;
            const int n_g = sn0 + n_l;
            float v0 = 0.f, v1 = 0.f, v2 = 0.f, v3 = 0.f;
            if (n_g < N_DICT) {
                v0 = P[(kq * 4 + 0) * N_DICT + n_g];
                v1 = P[(kq * 4 + 1) * N_DICT + n_g];
                v2 = P[(kq * 4 + 2) * N_DICT + n_g];
                v3 = P[(kq * 4 + 3) * N_DICT + n_g];
            }
            ushort4 H, L;
            H.x = bf16h(v0); L.x = bf16h(v0 - bf16f(H.x));
            H.y = bf16h(v1); L.y = bf16h(v1 - bf16f(H.y));
            H.z = bf16h(v2); L.z = bf16h(v2 - bf16f(H.z));
            H.w = bf16h(v3); L.w = bf16h(v3 - bf16f(H.w));
            ys[((arr * 2 + 0) * 16 + kq) * 64 + n_l] = H;
            ys[((arr * 2 + 1) * 16 + kq) * 64 + n_l] = L;
        }
        __syncthreads();
        v4f acc[2][2][4];
#pragma unroll
        for (int bt = 0; bt < 2; ++bt)
#pragma unroll
            for (int nt = 0; nt < 2; ++nt)
#pragma unroll
                for (int d = 0; d < 4; ++d) acc[bt][nt][d] = (v4f){0.f, 0.f, 0.f, 0.f};
#pragma unroll
        for (int h = 0; h < 2; ++h) {
            const int kq0 = h * 8 + quad * 2;
#pragma unroll
            for (int nt = 0; nt < 2; ++nt) {
                const int nrow = (wn * 2 + nt) * 16 + col;
                v8s yf[4];
#pragma unroll
                for (int t = 0; t < 4; ++t) {
                    ushort4 lo = ys[(t * 16 + kq0    ) * 64 + nrow];
                    ushort4 hi = ys[(t * 16 + kq0 + 1) * 64 + nrow];
                    v8s f;
                    f[0] = (short)lo.x; f[1] = (short)lo.y; f[2] = (short)lo.z; f[3] = (short)lo.w;
                    f[4] = (short)hi.x; f[5] = (short)hi.y; f[6] = (short)hi.z; f[7] = (short)hi.w;
                    yf[t] = f;
                }
#pragma unroll
                for (int bt = 0; bt < 2; ++bt) {
#define MF(A, B, C) C = __builtin_amdgcn_mfma_f32_16x16x32_bf16(A, B, C, 0, 0, 0)
                    MF(yf[0], fh[0][bt][h], acc[bt][nt][0]);
                    MF(yf[0], fl[0][bt][h], acc[bt][nt][0]);
                    MF(yf[1], fh[0][bt][h], acc[bt][nt][0]);
                    MF(yf[2], fh[0][bt][h], acc[bt][nt][1]);
                    MF(yf[2], fl[0][bt][h], acc[bt][nt][1]);
                    MF(yf[3], fh[0][bt][h], acc[bt][nt][1]);
                    MF(yf[0], fh[1][bt][h], acc[bt][nt][2]);
                    MF(yf[0], fl[1][bt][h], acc[bt][nt][2]);
                    MF(yf[1], fh[1][bt][h], acc[bt][nt][2]);
                    MF(yf[2], fh[1][bt][h], acc[bt][nt][3]);
                    MF(yf[2], fl[1][bt][h], acc[bt][nt][3]);
                    MF(yf[3], fh[1][bt][h], acc[bt][nt][3]);
#undef MF
                }
            }
        }
#pragma unroll
        for (int bt = 0; bt < 2; ++bt)
#pragma unroll
            for (int nt = 0; nt < 2; ++nt) {
                v4f RR = acc[bt][nt][0], RI = acc[bt][nt][1];
                v4f S1 = acc[bt][nt][2], S2 = acc[bt][nt][3];
#pragma unroll
                for (int r = 0; r < 4; ++r) {
                    float s = fmaf(RR[r], RR[r], fmaf(RI[r], RI[r],
                              fmaf(S1[r], S1[r], S2[r] * S2[r])));
                    const int n_g = sn0 + (wn * 2 + nt) * 16 + quad * 4 + r;
                    unsigned long long p =
                        (((unsigned long long)__float_as_uint(s)) << 32)
                      | (unsigned long long)(0xFFFFFFFFu - (unsigned)n_g);
                    if (p > t2a[bt])      { t2b[bt] = t2a[bt]; t2a[bt] = p; }
                    else if (p > t2b[bt]) { t2b[bt] = p; }
                }
            }
    }
    unsigned long long fa1[2], fa2[2];
#pragma unroll
    for (int bt = 0; bt < 2; ++bt) {
        unsigned long long a1 = t2a[bt], a2 = t2b[bt];
#pragma unroll
        for (int d = 16; d <= 32; d <<= 1) {
            unsigned long long b1 = __shfl_xor(a1, d, 64);
            unsigned long long b2 = __shfl_xor(a2, d, 64);
            unsigned long long m1 = u64max(a1, b1);
            unsigned long long m2 = u64max(u64min(a1, b1), u64max(a2, b2));
            a1 = m1; a2 = m2;
        }
        fa1[bt] = a1; fa2[bt] = a2;
    }
    __syncthreads();
    if (wn == 1 && lane < 16) {
#pragma unroll
        for (int bt = 0; bt < 2; ++bt) { xm[wb][bt][lane][0] = fa1[bt]; xm[wb][bt][lane][1] = fa2[bt]; }
    }
    __syncthreads();
    if (wn == 0 && lane < 16) {
#pragma unroll
        for (int bt = 0; bt < 2; ++bt) {
            unsigned long long b1 = xm[wb][bt][lane][0];
            unsigned long long b2 = xm[wb][bt][lane][1];
            unsigned long long m1 = u64max(fa1[bt], b1);
            unsigned long long m2 = u64max(u64min(fa1[bt], b1), u64max(fa2[bt], b2));
            const size_t vox = vox_w + bt * 16 + lane;
            cand[vox * 64 + chunk * 2 + 0] = m1;
            cand[vox * 64 + chunk * 2 + 1] = m2;
        }
    }
}

// ---------------------------------------------------------------------------
// Phase B: exact fp32 rescore of candidates within 1% of approx max.
// One wave per voxel; `slots` candidate slots (<=64).
// ---------------------------------------------------------------------------
__global__ __launch_bounds__(256) void rescore_k(
    const float* __restrict__ ir, const float* __restrict__ ii,
    const float* __restrict__ yr, const float* __restrict__ yi,
    const unsigned long long* __restrict__ cand, int slots, int* __restrict__ idx_sel)
{
    const int tid  = threadIdx.x;
    const int vox  = blockIdx.x * 4 + (tid >> 6);
    const int slot = tid & 63;

    unsigned long long p = (slot < slots) ? cand[(size_t)vox * slots + slot] : 0ull;
    float sa = __uint_as_float((unsigned int)(p >> 32));
    unsigned int nn = 0xFFFFFFFFu - (unsigned int)(p & 0xFFFFFFFFull);

    float amax = sa;
#pragma unroll
    for (int d = 1; d <= 32; d <<= 1) amax = fmaxf(amax, __shfl_xor(amax, d, 64));

    unsigned long long q = 0ull;
    if (nn < N_DICT && sa >= 0.99f * amax) {
        float rr = 0.f, ri = 0.f, s1 = 0.f, s2 = 0.f;
        for (int m = 0; m < M_TIME; ++m) {
            float a  = yr[(size_t)m * N_DICT + nn];
            float c  = yi[(size_t)m * N_DICT + nn];
            float vr = ir[m * B_VOX + vox];
            float vi = ii[m * B_VOX + vox];
            rr = fmaf(vr, a, rr); ri = fmaf(vr, c, ri);
            s1 = fmaf(vi, a, s1); s2 = fmaf(vi, c, s2);
        }
        float s = fmaf(rr, rr, fmaf(ri, ri, fmaf(s1, s1, s2 * s2)));
        q = (((unsigned long long)__float_as_uint(s)) << 32)
          | (unsigned long long)(0xFFFFFFFFu - nn);          // ties -> smaller n
    }
#pragma unroll
    for (int d = 1; d <= 32; d <<= 1) q = u64max(q, __shfl_xor(q, d, 64));
    if (slot == 0) idx_sel[vox] = (int)(0xFFFFFFFFu - (unsigned int)(q & 0xFFFFFFFFull));
}

// ---------------------------------------------------------------------------
// Last-resort fallback: fp32 brute-force argmax.
// ---------------------------------------------------------------------------
__global__ __launch_bounds__(256, 3) void argmax_naive(
    const float* __restrict__ ir, const float* __restrict__ ii,
    const float* __restrict__ yr, const float* __restrict__ yi,
    int* __restrict__ idxout)
{
    int b = blockIdx.x * 256 + threadIdx.x;
    float bs = -1.0f; int bn = 0;
    for (int n = 0; n < N_DICT; ++n) {
        float a_rr = 0.f, a_ri = 0.f, a_s1 = 0.f, a_s2 = 0.f;
        for (int m = 0; m < M_TIME; ++m) {
            float a = yr[m * N_DICT + n], c = yi[m * N_DICT + n];
            float vr = ir[m * B_VOX + b], vi = ii[m * B_VOX + b];
            a_rr = fmaf(vr, a, a_rr); a_ri = fmaf(vr, c, a_ri);
            a_s1 = fmaf(vi, a, a_s1); a_s2 = fmaf(vi, c, a_s2);
        }
        float sim = fmaf(a_rr, a_rr, fmaf(a_ri, a_ri, fmaf(a_s1, a_s1, a_s2 * a_s2)));
        if (sim > bs) { bs = sim; bn = n; }
    }
    idxout[b] = bn;
}

// ---------------------------------------------------------------------------
// Phase C: gather chosen column, compute scales, write 4 output rows.
// idxin aliases out row 3 (read-before-write, same thread — safe).
// ---------------------------------------------------------------------------
__global__ void finish_k(const float* __restrict__ ir, const float* __restrict__ ii,
                         const float* __restrict__ yr, const float* __restrict__ yi,
                         const float* __restrict__ inv, const float* __restrict__ x1,
                         const float* __restrict__ x2,
                         const int* __restrict__ idxin, float* __restrict__ out)
{
    int b = blockIdx.x * blockDim.x + threadIdx.x;
    int idx = idxin[b];
    float ar = 0.f, ai = 0.f;
    for (int m = 0; m < M_TIME; ++m) {
        float a  = yr[(size_t)m * N_DICT + idx];
        float c  = yi[(size_t)m * N_DICT + idx];
        float vr = ir[m * B_VOX + b];
        float vi = ii[m * B_VOX + b];
        ar = fmaf(a, vr, ar); ar = fmaf(c, vi, ar);     // yr*ir + yi*ii
        ai = fmaf(a, vi, ai); ai = fmaf(-c, vr, ai);    // yr*ii - yi*ir
    }
    float s = inv[idx];
    out[0 * B_VOX + b] = ar * s;
    out[1 * B_VOX + b] = ai * s;
    out[2 * B_VOX + b] = x1[idx];
    out[3 * B_VOX + b] = x2[idx];
}

extern "C" void kernel_launch(void* const* d_in, const int* in_sizes, int n_in,
                              void* d_out, int out_size, void* d_ws, size_t ws_size,
                              hipStream_t stream) {
    const float* ir  = (const float*)d_in[0];
    const float* ii  = (const float*)d_in[1];
    const float* yr  = (const float*)d_in[2];
    const float* yi  = (const float*)d_in[3];
    const float* inv = (const float*)d_in[4];
    const float* x1  = (const float*)d_in[5];
    const float* x2  = (const float*)d_in[6];
    float* out = (float*)d_out;
    int* idx_sel = (int*)(out + 3 * B_VOX);          // scratch in out row 3

    const size_t yp_bytes = (size_t)NTILES * 4096 * sizeof(ushort4);   // 10.26 MB

    // pick largest chunk count whose cand buffer fits alongside yp
    int CH = 0;
    for (int c = 16; c >= 4; c >>= 1) {
        size_t cand_bytes = (size_t)B_VOX * (2 * c) * sizeof(unsigned long long);
        if (ws_size >= cand_bytes + yp_bytes) { CH = c; break; }
    }

    if (CH > 0) {
        const int slots = 2 * CH;
        const int tpc   = (NTILES + CH - 1) / CH;
        unsigned long long* cand = (unsigned long long*)d_ws;
        ushort4* yp = (ushort4*)((char*)d_ws
                     + (size_t)B_VOX * slots * sizeof(unsigned long long));

        const int units = 2 * NTILES * 1024;
        split_y<<<(units + 255) / 256, 256, 0, stream>>>(yr, yi, yp);
        gemm_pre<<<dim3(B_VOX / 64, CH), 256, 0, stream>>>(ir, ii, yp, cand, tpc, slots);
        rescore_k<<<B_VOX / 4, 256, 0, stream>>>(ir, ii, yr, yi, cand, slots, idx_sel);
        finish_k<<<B_VOX / 256, 256, 0, stream>>>(ir, ii, yr, yi,
                                                  inv, x1, x2, idx_sel, out);
    } else if (ws_size >= (size_t)B_VOX * 64 * sizeof(unsigned long long)) {
        unsigned long long* cand = (unsigned long long*)d_ws;
        gemm_mfma<<<dim3(B_VOX / 64, R5_CH), 256, 0, stream>>>(ir, ii, yr, yi, cand);
        rescore_k<<<B_VOX / 4, 256, 0, stream>>>(ir, ii, yr, yi, cand, 64, idx_sel);
        finish_k<<<B_VOX / 256, 256, 0, stream>>>(ir, ii, yr, yi,
                                                  inv, x1, x2, idx_sel, out);
    } else {
        argmax_naive<<<B_VOX / 256, 256, 0, stream>>>(ir, ii, yr, yi, idx_sel);
        finish_k<<<B_VOX / 256, 256, 0, stream>>>(ir, ii, yr, yi,
                                                  inv, x1, x2, idx_sel, out);
    }
}